// Round 1
// 285.939 us; speedup vs baseline: 1.0342x; 1.0342x over previous
//
#include <hip/hip_runtime.h>

// Problem constants
#define B_ 8
#define C_ 64
#define H_ 240
#define W_ 320
#define HW_ (H_ * W_)      // 76800
#define HW4_ (HW_ / 4)     // 19200
#define K_ 10
#define ALPHA_ 0.02f
#define DELTA_ 0.5f
#define MIN_WEIGHT_ 50.0f

#define NCH 4              // channels per k1 block (one-hot amortization)
#define CB_ (C_ / NCH)     // 16 channel-blocks
#define Z1 8               // pixel splits in k1 -> 16*8*8 = 1024 blocks

// Workspace layout (floats):
//   [0, 5120)      sums[b*64+c][k]
//   [5120, 5200)   counts[b*10+k]
//   [5200, 5280)   S2[b*10+k]
//   [5280, 5360)   Nk[b*10+k]
//   [5360, 10480)  means[b*64+c][k] (normalized, written by k3 chunk-0 blocks;
//                  NOT memset — fully overwritten before k4 reads it)

// ---------------------------------------------------------------------------
// Kernel 1: masked channel sums + cluster counts.
// One-hot built ONCE per pixel, amortized over NCH channels -> 1 fmac per
// (pixel, channel, cluster) instead of cmp+cndmask+add per channel.
// grid (CB_, 8, Z1), block 256.
// ---------------------------------------------------------------------------
__global__ __launch_bounds__(256) void k1_sums(
    const float* __restrict__ x, const int* __restrict__ cm,
    float* __restrict__ sums, float* __restrict__ counts) {
  const int cb = blockIdx.x;       // channel block 0..15
  const int b = blockIdx.y;
  const int z = blockIdx.z;
  const int tid = threadIdx.x;
  const int c0 = cb * NCH;

  const int chunk = HW4_ / Z1;     // 2400
  const int lo = z * chunk;
  const int hi = lo + chunk;

  const float4* __restrict__ xp =
      (const float4*)(x + (size_t)(b * C_ + c0) * HW_);
  const int4* __restrict__ cp = (const int4*)(cm + (size_t)b * HW_);

  float acc[NCH][K_];
#pragma unroll
  for (int c = 0; c < NCH; ++c)
#pragma unroll
    for (int j = 0; j < K_; ++j) acc[c][j] = 0.f;

  float cnt[K_];
#pragma unroll
  for (int j = 0; j < K_; ++j) cnt[j] = 0.f;
  const bool do_cnt = (cb == 0);

  for (int i = lo + tid; i < hi; i += 256) {
    const int4 k4 = cp[i];

    // one-hot per pixel component, built once, reused for all NCH channels
    float oh0[K_], oh1[K_], oh2[K_], oh3[K_];
#pragma unroll
    for (int j = 0; j < K_; ++j) {
      oh0[j] = (k4.x == j) ? 1.f : 0.f;
      oh1[j] = (k4.y == j) ? 1.f : 0.f;
      oh2[j] = (k4.z == j) ? 1.f : 0.f;
      oh3[j] = (k4.w == j) ? 1.f : 0.f;
    }
    if (do_cnt) {
#pragma unroll
      for (int j = 0; j < K_; ++j)
        cnt[j] += (oh0[j] + oh1[j]) + (oh2[j] + oh3[j]);
    }

#pragma unroll
    for (int c = 0; c < NCH; ++c) {
      const float4 v = xp[c * HW4_ + i];
#pragma unroll
      for (int j = 0; j < K_; ++j) {
        acc[c][j] += v.x * oh0[j];
        acc[c][j] += v.y * oh1[j];
        acc[c][j] += v.z * oh2[j];
        acc[c][j] += v.w * oh3[j];
      }
    }
  }

  // wave-level reduce (wave = 64 lanes), then one atomic per wave per bin
#pragma unroll
  for (int c = 0; c < NCH; ++c) {
#pragma unroll
    for (int j = 0; j < K_; ++j) {
      float v = acc[c][j];
#pragma unroll
      for (int off = 32; off > 0; off >>= 1) v += __shfl_down(v, off, 64);
      if ((tid & 63) == 0)
        atomicAdd(&sums[(b * C_ + c0 + c) * K_ + j], v);
    }
  }
  if (do_cnt) {
#pragma unroll
    for (int j = 0; j < K_; ++j) {
      float v = cnt[j];
#pragma unroll
      for (int off = 32; off > 0; off >>= 1) v += __shfl_down(v, off, 64);
      if ((tid & 63) == 0) atomicAdd(&counts[b * K_ + j], v);
    }
  }
}

// ---------------------------------------------------------------------------
// Kernel 3: per-block means normalization (redundant, from sums/counts) +
// per-pixel intra distance -> S2/Nk per cluster.
// grid (300, 8), block 256 = 64 pixel-lanes x 4 channel-groups.
// chunk-0 blocks additionally publish normalized means for k4.
// (indtot removed: k4 derives it as sum(Nk).)
// ---------------------------------------------------------------------------
__global__ __launch_bounds__(256) void k3_intra(
    const float* __restrict__ x, const int* __restrict__ cm,
    const float* __restrict__ sums, const float* __restrict__ counts,
    float* __restrict__ means, float* __restrict__ S2,
    float* __restrict__ Nk) {
  const int b = blockIdx.y;
  const int chunk = blockIdx.x;
  const int tid = threadIdx.x;
  const int lane_p = tid & 63;   // pixel-unit lane (one float4 = 4 pixels)
  const int grp = tid >> 6;      // channel group 0..3

  __shared__ float mlds[C_ * K_];   // 640 floats, layout [c*10+k]
  __shared__ float nrm[K_];
  __shared__ float4 pd[256];        // partial dots per thread
  __shared__ float s2b[K_];
  __shared__ float nkb[K_];

  // ---- local means normalization ----
  for (int i = tid; i < C_ * K_; i += 256) {
    const int k = i % K_;
    mlds[i] = sums[b * C_ * K_ + i] / (counts[b * K_ + k] + 1e-10f);
  }
  if (tid < K_) { s2b[tid] = 0.f; nkb[tid] = 0.f; }
  __syncthreads();
  if (tid < K_) {
    float n2 = 0.f;
#pragma unroll
    for (int c = 0; c < C_; ++c) {
      const float mm = mlds[c * K_ + tid];
      n2 += mm * mm;
    }
    nrm[tid] = 1.f / fmaxf(sqrtf(n2), 1e-12f);
  }
  __syncthreads();
  for (int i = tid; i < C_ * K_; i += 256) mlds[i] *= nrm[i % K_];
  __syncthreads();
  if (chunk == 0) {
    for (int i = tid; i < C_ * K_; i += 256) means[b * C_ * K_ + i] = mlds[i];
  }

  // ---- intra distances ----
  const int p4 = chunk * 64 + lane_p;  // 0..19199
  const int4 k4 = ((const int4*)(cm + (size_t)b * HW_))[p4];
  const float4* __restrict__ xb = (const float4*)(x + (size_t)b * C_ * HW_);

  const int c0 = grp * (C_ / 4);
  // base pointers: channel index folds into the ds_read immediate offset
  const float* __restrict__ m0 = &mlds[c0 * K_ + k4.x];
  const float* __restrict__ m1 = &mlds[c0 * K_ + k4.y];
  const float* __restrict__ m2 = &mlds[c0 * K_ + k4.z];
  const float* __restrict__ m3 = &mlds[c0 * K_ + k4.w];

  float d0 = 0.f, d1 = 0.f, d2 = 0.f, d3 = 0.f;
#pragma unroll
  for (int cc = 0; cc < C_ / 4; ++cc) {
    const float4 v = xb[(c0 + cc) * HW4_ + p4];
    d0 += v.x * m0[cc * K_];
    d1 += v.y * m1[cc * K_];
    d2 += v.z * m2[cc * K_];
    d3 += v.w * m3[cc * K_];
  }
  pd[tid] = make_float4(d0, d1, d2, d3);
  __syncthreads();

  if (grp == 0) {
    float4 a = pd[lane_p];
    float4 bb = pd[lane_p + 64];
    float4 cc = pd[lane_p + 128];
    float4 dd = pd[lane_p + 192];
    const float i0 = 0.5f * (1.f - (a.x + bb.x + cc.x + dd.x));
    const float i1 = 0.5f * (1.f - (a.y + bb.y + cc.y + dd.y));
    const float i2 = 0.5f * (1.f - (a.z + bb.z + cc.z + dd.z));
    const float i3 = 0.5f * (1.f - (a.w + bb.w + cc.w + dd.w));

    atomicAdd(&s2b[k4.x], i0 * i0);
    atomicAdd(&s2b[k4.y], i1 * i1);
    atomicAdd(&s2b[k4.z], i2 * i2);
    atomicAdd(&s2b[k4.w], i3 * i3);
    atomicAdd(&nkb[k4.x], i0 > ALPHA_ ? 1.f : 0.f);
    atomicAdd(&nkb[k4.y], i1 > ALPHA_ ? 1.f : 0.f);
    atomicAdd(&nkb[k4.z], i2 > ALPHA_ ? 1.f : 0.f);
    atomicAdd(&nkb[k4.w], i3 > ALPHA_ ? 1.f : 0.f);
  }
  __syncthreads();

  if (tid < K_) {
    atomicAdd(&S2[b * K_ + tid], s2b[tid]);
    atomicAdd(&Nk[b * K_ + tid], nkb[tid]);
  }
}

// ---------------------------------------------------------------------------
// Kernel 4: inter hinge loss + finalize. One block, fully parallel tail.
// ---------------------------------------------------------------------------
__global__ __launch_bounds__(256) void k4_final(
    const float* __restrict__ means, const float* __restrict__ S2,
    const float* __restrict__ Nk, float* __restrict__ out) {
  const int tid = threadIdx.x;

  // hinge pairs (upper triangle, doubled for both orders)
  float acc_h = 0.f;
  for (int t = tid; t < B_ * 45; t += 256) {
    const int b = t / 45;
    int idx = t % 45;
    int k = 0, l = 0;
    for (k = 0; k < K_; ++k) {
      const int row = K_ - 1 - k;
      if (idx < row) { l = k + 1 + idx; break; }
      idx -= row;
    }
    float g = 0.f;
    for (int c = 0; c < C_; ++c)
      g += means[(b * C_ + c) * K_ + k] * means[(b * C_ + c) * K_ + l];
    const float inter_d = 0.5f * (1.f - g);
    const float h = fmaxf(DELTA_ - inter_d, 0.f);
    acc_h += 2.f * h * h;  // (k,l) and (l,k)
  }

  // intra partials + indicator total (= sum of Nk), parallel over 80 bins
  float acc_i = 0.f;
  float acc_n = 0.f;
  if (tid < B_ * K_) {
    const float nk = Nk[tid];
    acc_n = nk;
    const float w = fmaxf(nk, MIN_WEIGHT_) * (float)K_;
    acc_i = S2[tid] / w;
  }

  __shared__ float rh[256], ri[256], rn[256];
  rh[tid] = acc_h;
  ri[tid] = acc_i;
  rn[tid] = acc_n;
  __syncthreads();
  for (int s = 128; s > 0; s >>= 1) {
    if (tid < s) {
      rh[tid] += rh[tid + s];
      ri[tid] += ri[tid + s];
      rn[tid] += rn[tid + s];
    }
    __syncthreads();
  }
  if (tid == 0) {
    const float inter = rh[0] / (float)((K_ * (K_ - 1) / 2) * B_);
    float intra = ri[0] / (float)B_;
    if (!(rn[0] > 0.f)) intra = 0.f;
    out[0] = intra + inter;
    out[1] = intra;
    out[2] = inter;
  }
}

extern "C" void kernel_launch(void* const* d_in, const int* in_sizes, int n_in,
                              void* d_out, int out_size, void* d_ws, size_t ws_size,
                              hipStream_t stream) {
  const float* x = (const float*)d_in[0];
  const int* cm = (const int*)d_in[1];

  float* ws = (float*)d_ws;
  float* sums = ws;             // 5120
  float* counts = ws + 5120;    // 80
  float* S2 = ws + 5200;        // 80
  float* Nk = ws + 5280;        // 80
  float* means = ws + 5360;     // 5120 (no init needed)

  // ws is re-poisoned to 0xAA before every call — zero only the accumulators.
  hipMemsetAsync(d_ws, 0, 5360 * sizeof(float), stream);

  k1_sums<<<dim3(CB_, B_, Z1), 256, 0, stream>>>(x, cm, sums, counts);
  k3_intra<<<dim3(HW4_ / 64, B_), 256, 0, stream>>>(x, cm, sums, counts, means,
                                                    S2, Nk);
  k4_final<<<1, 256, 0, stream>>>(means, S2, Nk, (float*)d_out);
}